// Round 7
// baseline (510.041 us; speedup 1.0000x reference)
//
#include <hip/hip_runtime.h>
#include <hip/hip_bf16.h>
#include <math.h>

typedef __attribute__((ext_vector_type(4))) float f4_t;
typedef __attribute__((ext_vector_type(8))) short s8_t;

constexpr int Bc = 64;      // batches
constexpr int Tc = 1024;    // tokens per batch (H*W)
constexpr int Cc = 512;     // channels
constexpr int Ec = 5;       // experts
constexpr int HIDc = 2048;  // hidden

// async global->LDS, 16B per lane (linear LDS dest: wave-uniform base + lane*16)
__device__ __forceinline__ void async_copy16(const void* gsrc, void* ldst) {
  __builtin_amdgcn_global_load_lds(
      (const __attribute__((address_space(1))) unsigned int*)gsrc,
      (__attribute__((address_space(3))) unsigned int*)ldst, 16, 0, 0);
}

// tanh-form gelu, folded: gelu(x) = x * (1 - 1/(1+exp(2*0.79788456*(x+0.044715 x^3))))
// |err vs exact erf-gelu| ~ 2e-4 (<< bf16 rounding of h). 6 VALU + 2 trans.
__device__ __forceinline__ float gelu_f(float v) {
  float v2 = v * v;
  float z = v * (1.5957691216f + 0.0713548162f * v2);  // 2*c*(1+0.044715 v^2)
  float e = __expf(z);
  float r = __frcp_rn(1.0f + e);
  return v - v * r;  // x*(1 - 1/(1+e^z))
}

// ---------------- gating / prep ----------------

__global__ void k_prep(const float* __restrict__ x, ushort* __restrict__ xbf,
                       float* __restrict__ part) {
  int b = blockIdx.x, p = blockIdx.y, tid = threadIdx.x;
  const float4* xp = (const float4*)(x + ((size_t)b * Tc + (size_t)p * 128) * Cc);
  ushort4* op = (ushort4*)(xbf + ((size_t)b * Tc + (size_t)p * 128) * Cc);
  int c4 = tid & 127, r0 = tid >> 7;
  float4 s = {0.f, 0.f, 0.f, 0.f};
  for (int r = r0; r < 128; r += 2) {
    float4 v = xp[(size_t)r * 128 + c4];
    s.x += v.x; s.y += v.y; s.z += v.z; s.w += v.w;
    union { __hip_bfloat16 h[4]; ushort4 u; } cv;
    cv.h[0] = __float2bfloat16(v.x);
    cv.h[1] = __float2bfloat16(v.y);
    cv.h[2] = __float2bfloat16(v.z);
    cv.h[3] = __float2bfloat16(v.w);
    op[(size_t)r * 128 + c4] = cv.u;
  }
  __shared__ float4 sh[128];
  if (r0) sh[c4] = s;
  __syncthreads();
  if (!r0) {
    float4 o = sh[c4];
    s.x += o.x; s.y += o.y; s.z += o.z; s.w += o.w;
    ((float4*)part)[(size_t)(b * 8 + p) * 128 + c4] = s;
  }
}

__global__ void k_partial(const float* __restrict__ x, float* __restrict__ part) {
  int b = blockIdx.x, p = blockIdx.y, tid = threadIdx.x;
  const float* xp = x + ((size_t)b * Tc + (size_t)p * 128) * Cc;
  float s0 = 0.f, s1 = 0.f;
  for (int t = 0; t < 128; ++t) {
    s0 += xp[(size_t)t * Cc + tid];
    s1 += xp[(size_t)t * Cc + tid + 256];
  }
  part[(size_t)(b * 8 + p) * Cc + tid] = s0;
  part[(size_t)(b * 8 + p) * Cc + tid + 256] = s1;
}

__global__ void k_cvt_x(const float* __restrict__ src, ushort* __restrict__ dst, int n4) {
  int i = blockIdx.x * blockDim.x + threadIdx.x;
  int stride = gridDim.x * blockDim.x;
  const float4* s4 = (const float4*)src;
  ushort4* d4 = (ushort4*)dst;
  for (; i < n4; i += stride) {
    float4 v = s4[i];
    union { __hip_bfloat16 h[4]; ushort4 u; } cv;
    cv.h[0] = __float2bfloat16(v.x);
    cv.h[1] = __float2bfloat16(v.y);
    cv.h[2] = __float2bfloat16(v.z);
    cv.h[3] = __float2bfloat16(v.w);
    d4[i] = cv.u;
  }
}

__global__ void k_xg_logits(const float* __restrict__ part, const float* __restrict__ wg,
                            float* __restrict__ logits) {
  __shared__ float xg[Cc];
  __shared__ float red[Ec][4];
  int b = blockIdx.x, tid = threadIdx.x;
  for (int c = tid; c < Cc; c += 256) {
    float s = 0.f;
#pragma unroll
    for (int p = 0; p < 8; ++p) s += part[(size_t)(b * 8 + p) * Cc + c];
    xg[c] = s * (1.0f / 1024.0f);
  }
  __syncthreads();
  float le[Ec] = {0.f, 0.f, 0.f, 0.f, 0.f};
  for (int c = tid; c < Cc; c += 256) {
    float v = xg[c];
#pragma unroll
    for (int e = 0; e < Ec; ++e) le[e] += v * wg[c * Ec + e];
  }
#pragma unroll
  for (int e = 0; e < Ec; ++e) {
    float v = le[e];
#pragma unroll
    for (int off = 32; off > 0; off >>= 1) v += __shfl_down(v, off);
    if ((tid & 63) == 0) red[e][tid >> 6] = v;
  }
  __syncthreads();
  if (tid < Ec) {
    float v = red[tid][0] + red[tid][1] + red[tid][2] + red[tid][3];
    v = fminf(fmaxf(v, -50.f), 50.f);
    logits[b * Ec + tid] = v;
  }
}

__global__ void k_gate(const float* __restrict__ logits, int* __restrict__ idx,
                       float* __restrict__ loss_out) {
  __shared__ int cnt[Ec];
  int tid = threadIdx.x;
  if (tid < Ec) cnt[tid] = 0;
  __syncthreads();
  if (tid < Bc) {
    const float* lb = logits + tid * Ec;
    int best = 0;
    float bv = lb[0];
#pragma unroll
    for (int e = 1; e < Ec; ++e) {
      float v = lb[e];
      if (v > bv) { bv = v; best = e; }
    }
    idx[tid] = best;
    atomicAdd(&cnt[best], 1);
  }
  __syncthreads();
  if (tid == 0) {
    const float mean = (float)Bc / (float)Ec;
    float var = 0.f;
#pragma unroll
    for (int e = 0; e < Ec; ++e) {
      float d = (float)cnt[e] - mean;
      var += d * d;
    }
    var *= (1.0f / (Ec - 1));
    float loss = 2.f * (var / (mean * mean + 1e-10f));
    loss = fminf(fmaxf(loss, 0.f), 1000.f);
    *loss_out = loss;
  }
}

__global__ void k_transpose_cvt(const float* __restrict__ src, __hip_bfloat16* __restrict__ dst,
                                int K, int N) {
  __shared__ float tile[32][33];
  int e = blockIdx.z;
  int kb = blockIdx.y * 32, nb = blockIdx.x * 32;
  const float* s = src + (size_t)e * K * N;
  __hip_bfloat16* d = dst + (size_t)e * K * N;
  int lx = threadIdx.x & 31, ly = threadIdx.x >> 5;
#pragma unroll
  for (int r = 0; r < 4; ++r) {
    int k = kb + ly + r * 8;
    tile[ly + r * 8][lx] = s[(size_t)k * N + nb + lx];
  }
  __syncthreads();
#pragma unroll
  for (int r = 0; r < 4; ++r) {
    int n = nb + ly + r * 8;
    d[(size_t)n * K + kb + lx] = __float2bfloat16(tile[lx][ly + r * 8]);
  }
}

// =====================================================================
// PERSISTENT GEMMs: grid = 4*cb blocks (1/CU at cb=64).  Each block owns
// one 256-row M-panel and loops over ALL N-tiles (256 cols each):
// gemm1: 8 tiles x NT=8 K-steps = 64 warm steps, 1 prologue;
// gemm2: 2 tiles x NT=32      = 64 warm steps.
// Per K-step: 4-phase interleave (stage(s+1) split into phases 0/1),
// T2 both-sides LDS swizzle, T5 setprio.  gemm1 tile epilogue uses the
// just-consumed LDS buffer (always buf1: tile ends on odd s) as
// transpose scratch, barrier-fenced before the next stage overwrites it.
// =====================================================================

#define GEMM_PRELUDE(KDIM)                                               \
  int tid = threadIdx.x, l = tid & 63, w = tid >> 6;                     \
  int wr = w >> 2, wc = w & 3;                                           \
  const short* gA[4];                                                    \
  const short* gB[4];                                                    \
  int loff[4];                                                           \
  _Pragma("unroll")                                                      \
  for (int i = 0; i < 4; ++i) {                                          \
    int sp = i * 512 + tid;                                              \
    int r = sp >> 3;                                                     \
    int c8 = ((sp & 7) ^ (r & 7)) << 3;                                  \
    gA[i] = Ab + (size_t)r * (KDIM) + c8;                                \
    gB[i] = Bb + (size_t)r * (KDIM) + c8;                                \
    loff[i] = sp * 16;                                                   \
  }                                                                      \
  int abase = (wr * 128 + (l & 15)) * 128;                               \
  int bbase = (wc * 64 + (l & 15)) * 128;                                \
  int s0 = (((l >> 4)) ^ (l & 7)) << 4;                                  \
  int s1 = (((l >> 4) + 4) ^ (l & 7)) << 4;

#define BAR()                          \
  __builtin_amdgcn_s_barrier();        \
  asm volatile("" ::: "memory")

// phase p: read A-quad (fm = 2p, 2p+1), fire 16 MFMA
#define MPHASE(p)                                                            \
  _Pragma("unroll")                                                          \
  for (int j = 0; j < 2; ++j) {                                              \
    afr[j * 2 + 0] = *(const s8_t*)(As_ + abase + ((p) * 2 + j) * 2048 + s0);\
    afr[j * 2 + 1] = *(const s8_t*)(As_ + abase + ((p) * 2 + j) * 2048 + s1);\
  }                                                                          \
  __builtin_amdgcn_s_setprio(1);                                             \
  _Pragma("unroll")                                                          \
  for (int kk = 0; kk < 2; ++kk)                                             \
    _Pragma("unroll")                                                        \
    for (int j = 0; j < 2; ++j)                                              \
      _Pragma("unroll")                                                      \
      for (int fn = 0; fn < 4; ++fn)                                         \
        acc[(p) * 2 + j][fn] = __builtin_amdgcn_mfma_f32_16x16x32_bf16(      \
            afr[j * 2 + kk], bfr[fn * 2 + kk], acc[(p) * 2 + j][fn], 0, 0, 0);\
  __builtin_amdgcn_s_setprio(0);

// one K-step: cur buf = c; stage step snx (if do_st) with A k-off ka_, B
// byte-row-offset nb_ (tile n-offset*K + k-off)
#define KSTEP(c, do_st, ka_, nb_)                                        \
  {                                                                      \
    const char* As_ = (const char*)&lds[c][0][0];                        \
    const char* Bs_ = (const char*)&lds[c][1][0];                        \
    s8_t bfr[8], afr[4];                                                 \
    if (do_st) {                                                         \
      char* d_ = (char*)&lds[(c) ^ 1][0][0];                             \
      _Pragma("unroll")                                                  \
      for (int i = 0; i < 4; ++i) async_copy16(gA[i] + (ka_), d_ + loff[i]); \
    }                                                                    \
    _Pragma("unroll")                                                    \
    for (int fn = 0; fn < 4; ++fn) {                                     \
      bfr[fn * 2 + 0] = *(const s8_t*)(Bs_ + bbase + fn * 2048 + s0);    \
      bfr[fn * 2 + 1] = *(const s8_t*)(Bs_ + bbase + fn * 2048 + s1);    \
    }                                                                    \
    MPHASE(0)                                                            \
    BAR();                                                               \
    if (do_st) {                                                         \
      char* d_ = (char*)&lds[(c) ^ 1][1][0];                             \
      _Pragma("unroll")                                                  \
      for (int i = 0; i < 4; ++i) async_copy16(gB[i] + (nb_), d_ + loff[i]); \
    }                                                                    \
    MPHASE(1)                                                            \
    BAR();                                                               \
    MPHASE(2)                                                            \
    BAR();                                                               \
    MPHASE(3)                                                            \
    if (do_st) { asm volatile("s_waitcnt vmcnt(0)" ::: "memory"); }      \
    BAR();                                                               \
  }

// GEMM1: h = gelu(x @ W1[e] + b1[e]); A xbf [cb][1024][512], B w1t [E][2048][512]
__global__ __launch_bounds__(512, 2) void k_gemm1(
    const __hip_bfloat16* __restrict__ xbf, const __hip_bfloat16* __restrict__ w1t,
    const float* __restrict__ b1, const int* __restrict__ idx, int b0,
    __hip_bfloat16* __restrict__ h) {
  constexpr int K = Cc;        // 512
  constexpr int N = HIDc;      // 2048
  constexpr int NT = 8;        // K-steps per tile
  constexpr int NSTEPS = 64;   // 8 tiles x 8
  __shared__ short lds[2][2][256 * 64];  // 128 KB

  int bz = blockIdx.x >> 2, my = blockIdx.x & 3;
  int e = idx[b0 + bz];
  int m0 = my * 256;
  const short* Ab = (const short*)xbf + ((size_t)bz * Tc + m0) * K;
  const short* Bb = (const short*)w1t + (size_t)e * N * K;

  GEMM_PRELUDE(K)
  f4_t acc[8][4] = {};

  short* hb = (short*)(h + (size_t)bz * Tc * N);
  const float* bias = b1 + (size_t)e * N;

  // prologue: stage step 0 (tile 0)
  {
    char* da = (char*)&lds[0][0][0];
    char* db = (char*)&lds[0][1][0];
#pragma unroll
    for (int i = 0; i < 4; ++i) async_copy16(gA[i], da + loff[i]);
#pragma unroll
    for (int i = 0; i < 4; ++i) async_copy16(gB[i], db + loff[i]);
  }
  asm volatile("s_waitcnt vmcnt(0)" ::: "memory");
  BAR();

#pragma unroll 2
  for (int s = 0; s < NSTEPS; ++s) {
    int cur = s & 1;
    int snx = s + 1;
    int ka = (snx & (NT - 1)) * 64;
    size_t nb = (size_t)(snx >> 3) * 256 * K + ka;
    KSTEP(cur, snx < NSTEPS, ka, nb)

    if ((s & (NT - 1)) == NT - 1) {
      // tile epilogue (tile = s>>3). cur==1 always (NT even, last step odd):
      // buf1 just consumed -> transpose scratch. 4 passes x 32 rows,
      // per-wave chunk 32x72 shorts (4608B) x8 = 36.9KB <= 64KB.
      int n0e = (s >> 3) * 256;
      short* chunk = &lds[1][0][0] + w * 2304;
      int cc2 = (l & 7) * 8;
#pragma unroll
      for (int pp = 0; pp < 4; ++pp) {
#pragma unroll
        for (int fn = 0; fn < 4; ++fn) {
          float bv = bias[n0e + wc * 64 + fn * 16 + (l & 15)];
#pragma unroll
          for (int fi = 0; fi < 2; ++fi) {
            int rl = fi * 16 + ((l >> 4) << 2);
#pragma unroll
            for (int j = 0; j < 4; ++j) {
              float v = gelu_f(acc[pp * 2 + fi][fn][j] + bv);
              chunk[(rl + j) * 72 + fn * 16 + (l & 15)] =
                  (short)__bfloat16_as_ushort(__float2bfloat16(v));
            }
          }
        }
#pragma unroll
        for (int q = 0; q < 4; ++q) {
          int rr = q * 8 + (l >> 3);
          s8_t v = *(const s8_t*)(chunk + rr * 72 + cc2);
          *(s8_t*)(hb + (size_t)(m0 + wr * 128 + pp * 32 + rr) * N + n0e + wc * 64 + cc2) = v;
        }
        // WAR fence between passes (reads of pass pp before writes of pp+1)
        asm volatile("s_waitcnt lgkmcnt(0)" ::: "memory");
      }
      // reset accumulator for next tile
#pragma unroll
      for (int fm = 0; fm < 8; ++fm)
#pragma unroll
        for (int fn = 0; fn < 4; ++fn) acc[fm][fn] = (f4_t){0.f, 0.f, 0.f, 0.f};
      // all waves done with scratch before next step stages into buf1
      BAR();
    }
  }
}

// GEMM2: y = h @ W2[e] + b2[e]; A h [cb][1024][2048], B w2t [E][512][2048]
__global__ __launch_bounds__(512, 2) void k_gemm2(
    const __hip_bfloat16* __restrict__ h, const __hip_bfloat16* __restrict__ w2t,
    const float* __restrict__ b2, const int* __restrict__ idx, int b0,
    float* __restrict__ out) {
  constexpr int K = HIDc;      // 2048
  constexpr int N = Cc;        // 512
  constexpr int NT = 32;       // K-steps per tile
  constexpr int NSTEPS = 64;   // 2 tiles x 32
  __shared__ short lds[2][2][256 * 64];  // 128 KB

  int bz = blockIdx.x >> 2, my = blockIdx.x & 3;
  int e = idx[b0 + bz];
  int m0 = my * 256;
  const short* Ab = (const short*)h + ((size_t)bz * Tc + m0) * K;
  const short* Bb = (const short*)w2t + (size_t)e * N * K;

  GEMM_PRELUDE(K)
  f4_t acc[8][4] = {};

  float* ob = out + (size_t)(b0 + bz) * Tc * N;
  const float* bias = b2 + (size_t)e * N;

  {
    char* da = (char*)&lds[0][0][0];
    char* db = (char*)&lds[0][1][0];
#pragma unroll
    for (int i = 0; i < 4; ++i) async_copy16(gA[i], da + loff[i]);
#pragma unroll
    for (int i = 0; i < 4; ++i) async_copy16(gB[i], db + loff[i]);
  }
  asm volatile("s_waitcnt vmcnt(0)" ::: "memory");
  BAR();

#pragma unroll 2
  for (int s = 0; s < NSTEPS; ++s) {
    int cur = s & 1;
    int snx = s + 1;
    int ka = (snx & (NT - 1)) * 64;
    size_t nb = (size_t)(snx >> 5) * 256 * K + ka;
    KSTEP(cur, snx < NSTEPS, ka, nb)

    if ((s & (NT - 1)) == NT - 1) {
      // tile epilogue: direct f32 stores (no LDS), then reset acc
      int n0e = (s >> 5) * 256;
#pragma unroll
      for (int fn = 0; fn < 4; ++fn) {
        int col = n0e + wc * 64 + fn * 16 + (l & 15);
        float bv = bias[col];
#pragma unroll
        for (int fm = 0; fm < 8; ++fm) {
          int rbase = m0 + wr * 128 + fm * 16 + ((l >> 4) << 2);
#pragma unroll
          for (int j = 0; j < 4; ++j) {
            ob[(size_t)(rbase + j) * N + col] = acc[fm][fn][j] + bv;
          }
        }
      }
#pragma unroll
      for (int fm = 0; fm < 8; ++fm)
#pragma unroll
        for (int fn = 0; fn < 4; ++fn) acc[fm][fn] = (f4_t){0.f, 0.f, 0.f, 0.f};
    }
  }
}

extern "C" void kernel_launch(void* const* d_in, const int* in_sizes, int n_in,
                              void* d_out, int out_size, void* d_ws, size_t ws_size,
                              hipStream_t stream) {
  const float* x  = (const float*)d_in[0];
  const float* wg = (const float*)d_in[1];
  const float* W1 = (const float*)d_in[2];
  const float* b1 = (const float*)d_in[3];
  const float* W2 = (const float*)d_in[4];
  const float* b2 = (const float*)d_in[5];
  float* out = (float*)d_out;

  char* ws = (char*)d_ws;
  size_t off = 0;
  float* part = (float*)(ws + off); off += (size_t)Bc * 8 * Cc * 4;
  float* logits = (float*)(ws + off); off += (size_t)Bc * Ec * 4;
  int* idx = (int*)(ws + off); off += (size_t)Bc * 4;
  off = (off + 255) & ~(size_t)255;
  __hip_bfloat16* w1t = (__hip_bfloat16*)(ws + off); off += (size_t)Ec * HIDc * Cc * 2;
  __hip_bfloat16* w2t = (__hip_bfloat16*)(ws + off); off += (size_t)Ec * HIDc * Cc * 2;
  size_t dynoff = (off + 255) & ~(size_t)255;

  const size_t x_all = (size_t)Bc * Tc * Cc * 2;   // 64 MB
  const size_t x_per_b = (size_t)Tc * Cc * 2;      // 1 MB
  const size_t h_per_b = (size_t)Tc * HIDc * 2;    // 4 MB

  k_transpose_cvt<<<dim3(HIDc / 32, Cc / 32, Ec), 256, 0, stream>>>(W1, w1t, Cc, HIDc);
  k_transpose_cvt<<<dim3(Cc / 32, HIDc / 32, Ec), 256, 0, stream>>>(W2, w2t, HIDc, Cc);

  if (ws_size >= dynoff + x_all + h_per_b) {
    __hip_bfloat16* xbf = (__hip_bfloat16*)(ws + dynoff);
    __hip_bfloat16* hbf = (__hip_bfloat16*)(ws + dynoff + x_all);
    int cb = (int)((ws_size - dynoff - x_all) / h_per_b);
    if (cb > Bc) cb = Bc;

    k_prep<<<dim3(Bc, 8), 256, 0, stream>>>(x, (ushort*)xbf, part);
    k_xg_logits<<<dim3(Bc), 256, 0, stream>>>(part, wg, logits);
    k_gate<<<dim3(1), 256, 0, stream>>>(logits, idx, out + ((size_t)out_size - 1));

    for (int b0 = 0; b0 < Bc; b0 += cb) {
      int c = (Bc - b0) < cb ? (Bc - b0) : cb;
      const __hip_bfloat16* xc = xbf + (size_t)b0 * Tc * Cc;
      k_gemm1<<<dim3(4 * c), 512, 0, stream>>>(xc, w1t, b1, idx, b0, hbf);
      k_gemm2<<<dim3(4 * c), 512, 0, stream>>>(hbf, w2t, b2, idx, b0, out);
    }
  } else {
    size_t avail = ws_size > dynoff ? ws_size - dynoff : 0;
    int cb = (int)(avail / (x_per_b + h_per_b));
    if (cb > Bc) cb = Bc;
    if (cb < 1) cb = 1;
    __hip_bfloat16* xbf = (__hip_bfloat16*)(ws + dynoff);
    __hip_bfloat16* hbf = (__hip_bfloat16*)(ws + dynoff + (size_t)cb * x_per_b);

    k_partial<<<dim3(Bc, 8), 256, 0, stream>>>(x, part);
    k_xg_logits<<<dim3(Bc), 256, 0, stream>>>(part, wg, logits);
    k_gate<<<dim3(1), 256, 0, stream>>>(logits, idx, out + ((size_t)out_size - 1));

    for (int b0 = 0; b0 < Bc; b0 += cb) {
      int c = (Bc - b0) < cb ? (Bc - b0) : cb;
      int n4 = c * (Tc * Cc / 4);
      k_cvt_x<<<dim3(1024), 256, 0, stream>>>(x + (size_t)b0 * Tc * Cc, (ushort*)xbf, n4);
      k_gemm1<<<dim3(4 * c), 512, 0, stream>>>(xbf, w1t, b1, idx, b0, hbf);
      k_gemm2<<<dim3(4 * c), 512, 0, stream>>>(hbf, w2t, b2, idx, b0, out);
    }
  }
}

// Round 8
// 436.789 us; speedup vs baseline: 1.1677x; 1.1677x over previous
//
#include <hip/hip_runtime.h>
#include <hip/hip_bf16.h>
#include <math.h>

typedef __attribute__((ext_vector_type(4))) float f4_t;
typedef __attribute__((ext_vector_type(8))) short s8_t;

constexpr int Bc = 64;      // batches
constexpr int Tc = 1024;    // tokens per batch (H*W)
constexpr int Cc = 512;     // channels
constexpr int Ec = 5;       // experts
constexpr int HIDc = 2048;  // hidden

// async global->LDS, 16B per lane (linear LDS dest: wave-uniform base + lane*16)
__device__ __forceinline__ void async_copy16(const void* gsrc, void* ldst) {
  __builtin_amdgcn_global_load_lds(
      (const __attribute__((address_space(1))) unsigned int*)gsrc,
      (__attribute__((address_space(3))) unsigned int*)ldst, 16, 0, 0);
}

// tanh-form gelu, folded. |err vs exact erf-gelu| ~ 2e-4 (<< bf16 rounding).
__device__ __forceinline__ float gelu_f(float v) {
  float v2 = v * v;
  float z = v * (1.5957691216f + 0.0713548162f * v2);
  float e = __expf(z);
  float r = __frcp_rn(1.0f + e);
  return v - v * r;
}

// ---------------- gating / prep ----------------

__global__ void k_prep(const float* __restrict__ x, ushort* __restrict__ xbf,
                       float* __restrict__ part) {
  int b = blockIdx.x, p = blockIdx.y, tid = threadIdx.x;
  const float4* xp = (const float4*)(x + ((size_t)b * Tc + (size_t)p * 128) * Cc);
  ushort4* op = (ushort4*)(xbf + ((size_t)b * Tc + (size_t)p * 128) * Cc);
  int c4 = tid & 127, r0 = tid >> 7;
  float4 s = {0.f, 0.f, 0.f, 0.f};
  for (int r = r0; r < 128; r += 2) {
    float4 v = xp[(size_t)r * 128 + c4];
    s.x += v.x; s.y += v.y; s.z += v.z; s.w += v.w;
    union { __hip_bfloat16 h[4]; ushort4 u; } cv;
    cv.h[0] = __float2bfloat16(v.x);
    cv.h[1] = __float2bfloat16(v.y);
    cv.h[2] = __float2bfloat16(v.z);
    cv.h[3] = __float2bfloat16(v.w);
    op[(size_t)r * 128 + c4] = cv.u;
  }
  __shared__ float4 sh[128];
  if (r0) sh[c4] = s;
  __syncthreads();
  if (!r0) {
    float4 o = sh[c4];
    s.x += o.x; s.y += o.y; s.z += o.z; s.w += o.w;
    ((float4*)part)[(size_t)(b * 8 + p) * 128 + c4] = s;
  }
}

__global__ void k_partial(const float* __restrict__ x, float* __restrict__ part) {
  int b = blockIdx.x, p = blockIdx.y, tid = threadIdx.x;
  const float* xp = x + ((size_t)b * Tc + (size_t)p * 128) * Cc;
  float s0 = 0.f, s1 = 0.f;
  for (int t = 0; t < 128; ++t) {
    s0 += xp[(size_t)t * Cc + tid];
    s1 += xp[(size_t)t * Cc + tid + 256];
  }
  part[(size_t)(b * 8 + p) * Cc + tid] = s0;
  part[(size_t)(b * 8 + p) * Cc + tid + 256] = s1;
}

__global__ void k_cvt_x(const float* __restrict__ src, ushort* __restrict__ dst, int n4) {
  int i = blockIdx.x * blockDim.x + threadIdx.x;
  int stride = gridDim.x * blockDim.x;
  const float4* s4 = (const float4*)src;
  ushort4* d4 = (ushort4*)dst;
  for (; i < n4; i += stride) {
    float4 v = s4[i];
    union { __hip_bfloat16 h[4]; ushort4 u; } cv;
    cv.h[0] = __float2bfloat16(v.x);
    cv.h[1] = __float2bfloat16(v.y);
    cv.h[2] = __float2bfloat16(v.z);
    cv.h[3] = __float2bfloat16(v.w);
    d4[i] = cv.u;
  }
}

__global__ void k_xg_logits(const float* __restrict__ part, const float* __restrict__ wg,
                            float* __restrict__ logits) {
  __shared__ float xg[Cc];
  __shared__ float red[Ec][4];
  int b = blockIdx.x, tid = threadIdx.x;
  for (int c = tid; c < Cc; c += 256) {
    float s = 0.f;
#pragma unroll
    for (int p = 0; p < 8; ++p) s += part[(size_t)(b * 8 + p) * Cc + c];
    xg[c] = s * (1.0f / 1024.0f);
  }
  __syncthreads();
  float le[Ec] = {0.f, 0.f, 0.f, 0.f, 0.f};
  for (int c = tid; c < Cc; c += 256) {
    float v = xg[c];
#pragma unroll
    for (int e = 0; e < Ec; ++e) le[e] += v * wg[c * Ec + e];
  }
#pragma unroll
  for (int e = 0; e < Ec; ++e) {
    float v = le[e];
#pragma unroll
    for (int off = 32; off > 0; off >>= 1) v += __shfl_down(v, off);
    if ((tid & 63) == 0) red[e][tid >> 6] = v;
  }
  __syncthreads();
  if (tid < Ec) {
    float v = red[tid][0] + red[tid][1] + red[tid][2] + red[tid][3];
    v = fminf(fmaxf(v, -50.f), 50.f);
    logits[b * Ec + tid] = v;
  }
}

__global__ void k_gate(const float* __restrict__ logits, int* __restrict__ idx,
                       float* __restrict__ loss_out) {
  __shared__ int cnt[Ec];
  int tid = threadIdx.x;
  if (tid < Ec) cnt[tid] = 0;
  __syncthreads();
  if (tid < Bc) {
    const float* lb = logits + tid * Ec;
    int best = 0;
    float bv = lb[0];
#pragma unroll
    for (int e = 1; e < Ec; ++e) {
      float v = lb[e];
      if (v > bv) { bv = v; best = e; }
    }
    idx[tid] = best;
    atomicAdd(&cnt[best], 1);
  }
  __syncthreads();
  if (tid == 0) {
    const float mean = (float)Bc / (float)Ec;
    float var = 0.f;
#pragma unroll
    for (int e = 0; e < Ec; ++e) {
      float d = (float)cnt[e] - mean;
      var += d * d;
    }
    var *= (1.0f / (Ec - 1));
    float loss = 2.f * (var / (mean * mean + 1e-10f));
    loss = fminf(fmaxf(loss, 0.f), 1000.f);
    *loss_out = loss;
  }
}

__global__ void k_transpose_cvt(const float* __restrict__ src, __hip_bfloat16* __restrict__ dst,
                                int K, int N) {
  __shared__ float tile[32][33];
  int e = blockIdx.z;
  int kb = blockIdx.y * 32, nb = blockIdx.x * 32;
  const float* s = src + (size_t)e * K * N;
  __hip_bfloat16* d = dst + (size_t)e * K * N;
  int lx = threadIdx.x & 31, ly = threadIdx.x >> 5;
#pragma unroll
  for (int r = 0; r < 4; ++r) {
    int k = kb + ly + r * 8;
    tile[ly + r * 8][lx] = s[(size_t)k * N + nb + lx];
  }
  __syncthreads();
#pragma unroll
  for (int r = 0; r < 4; ++r) {
    int n = nb + ly + r * 8;
    d[(size_t)n * K + kb + lx] = __float2bfloat16(tile[lx][ly + r * 8]);
  }
}

// =====================================================================
// m201-style 8-phase schedule on 256x256/BK=64/8-wave geometry, dbuf LDS,
// T2 both-sides swizzle, T5 setprio.  Per K-tile t: 4 phases; phase q =
// { [q0: bfr reads] afr quad reads || stage ONE half-tile -> s_barrier ->
//   lgkmcnt(0)+sched_barrier -> setprio+16 MFMA -> [q3: counted vmcnt]
//   -> s_barrier }.
// Stage order: q0 Alo(t+1), q1 Ahi(t+1), q2 Blo(t+2), q3 Bhi(t+2) — each
// region is provably free (closing barriers) at its issue phase.
// vmcnt(4) at q3-end (before the closing barrier => per-wave drain becomes
// global) waits A(t+1)+B(t+1), leaves B(t+2)'s 4 loads in flight. Never 0
// mid-loop (T4); vmcnt(0) only at the tail.
// =====================================================================

#define GEMM_PRELUDE(KDIM)                                               \
  int tid = threadIdx.x, l = tid & 63, w = tid >> 6;                     \
  int wr = w >> 2, wc = w & 3;                                           \
  const short* gA[4];                                                    \
  const short* gB[4];                                                    \
  int loff[4];                                                           \
  _Pragma("unroll")                                                      \
  for (int i = 0; i < 4; ++i) {                                          \
    int sp = i * 512 + tid;                                              \
    int r = sp >> 3;                                                     \
    int c8 = ((sp & 7) ^ (r & 7)) << 3;                                  \
    gA[i] = Ab + (size_t)r * (KDIM) + c8;                                \
    gB[i] = Bb + (size_t)r * (KDIM) + c8;                                \
    loff[i] = sp * 16;                                                   \
  }                                                                      \
  int abase = (wr * 128 + (l & 15)) * 128;                               \
  int bbase = (wc * 64 + (l & 15)) * 128;                                \
  int s0 = (((l >> 4)) ^ (l & 7)) << 4;                                  \
  int s1 = (((l >> 4) + 4) ^ (l & 7)) << 4;

#define STAGE_A_HALF(buf, h, kt)                                         \
  {                                                                      \
    char* d_ = (char*)&lds[buf][0][0];                                   \
    int k0_ = (kt) * 64;                                                 \
    async_copy16(gA[2 * (h)] + k0_, d_ + loff[2 * (h)]);                 \
    async_copy16(gA[2 * (h) + 1] + k0_, d_ + loff[2 * (h) + 1]);         \
  }
#define STAGE_B_HALF(buf, h, kt)                                         \
  {                                                                      \
    char* d_ = (char*)&lds[buf][1][0];                                   \
    int k0_ = (kt) * 64;                                                 \
    async_copy16(gB[2 * (h)] + k0_, d_ + loff[2 * (h)]);                 \
    async_copy16(gB[2 * (h) + 1] + k0_, d_ + loff[2 * (h) + 1]);         \
  }

// one phase: q = quad index (0..3)
#define PH8(q, tt, NTv)                                                      \
  {                                                                          \
    const char* As_ = (const char*)&lds[(tt) & 1][0][0];                     \
    const char* Bs_ = (const char*)&lds[(tt) & 1][1][0];                     \
    if ((q) == 0) {                                                          \
      _Pragma("unroll")                                                      \
      for (int fn = 0; fn < 4; ++fn) {                                       \
        bfr[fn * 2 + 0] = *(const s8_t*)(Bs_ + bbase + fn * 2048 + s0);      \
        bfr[fn * 2 + 1] = *(const s8_t*)(Bs_ + bbase + fn * 2048 + s1);      \
      }                                                                      \
    }                                                                        \
    afr[0] = *(const s8_t*)(As_ + abase + ((q) * 2 + 0) * 2048 + s0);        \
    afr[1] = *(const s8_t*)(As_ + abase + ((q) * 2 + 0) * 2048 + s1);        \
    afr[2] = *(const s8_t*)(As_ + abase + ((q) * 2 + 1) * 2048 + s0);        \
    afr[3] = *(const s8_t*)(As_ + abase + ((q) * 2 + 1) * 2048 + s1);        \
    if ((q) == 0 && (tt) + 1 < (NTv)) STAGE_A_HALF(((tt) + 1) & 1, 0, (tt) + 1) \
    if ((q) == 1 && (tt) + 1 < (NTv)) STAGE_A_HALF(((tt) + 1) & 1, 1, (tt) + 1) \
    if ((q) == 2 && (tt) + 2 < (NTv)) STAGE_B_HALF((tt) & 1, 0, (tt) + 2)    \
    if ((q) == 3 && (tt) + 2 < (NTv)) STAGE_B_HALF((tt) & 1, 1, (tt) + 2)    \
    __builtin_amdgcn_s_barrier();                                            \
    asm volatile("s_waitcnt lgkmcnt(0)" ::: "memory");                       \
    __builtin_amdgcn_sched_barrier(0);                                       \
    __builtin_amdgcn_s_setprio(1);                                           \
    _Pragma("unroll")                                                        \
    for (int kk = 0; kk < 2; ++kk)                                           \
      _Pragma("unroll")                                                      \
      for (int j = 0; j < 2; ++j)                                            \
        _Pragma("unroll")                                                    \
        for (int fn = 0; fn < 4; ++fn)                                       \
          acc[(q) * 2 + j][fn] = __builtin_amdgcn_mfma_f32_16x16x32_bf16(    \
              afr[j * 2 + kk], bfr[fn * 2 + kk], acc[(q) * 2 + j][fn], 0, 0, 0); \
    __builtin_amdgcn_s_setprio(0);                                           \
    if ((q) == 3) {                                                          \
      if ((tt) + 2 < (NTv)) {                                                \
        asm volatile("s_waitcnt vmcnt(4)" ::: "memory");                     \
      } else if ((tt) + 1 < (NTv)) {                                         \
        asm volatile("s_waitcnt vmcnt(0)" ::: "memory");                     \
      }                                                                      \
    }                                                                        \
    __builtin_amdgcn_s_barrier();                                            \
    asm volatile("" ::: "memory");                                           \
  }

#define KLOOP8(NTv)                                                      \
  s8_t bfr[8], afr[4];                                                   \
  STAGE_B_HALF(0, 0, 0)                                                  \
  STAGE_B_HALF(0, 1, 0)                                                  \
  STAGE_A_HALF(0, 0, 0)                                                  \
  STAGE_A_HALF(0, 1, 0)                                                  \
  STAGE_B_HALF(1, 0, 1)                                                  \
  STAGE_B_HALF(1, 1, 1)                                                  \
  asm volatile("s_waitcnt vmcnt(4)" ::: "memory");                       \
  __builtin_amdgcn_s_barrier();                                          \
  asm volatile("" ::: "memory");                                         \
  _Pragma("unroll 2")                                                    \
  for (int t = 0; t < (NTv); ++t) {                                      \
    PH8(0, t, NTv)                                                       \
    PH8(1, t, NTv)                                                       \
    PH8(2, t, NTv)                                                       \
    PH8(3, t, NTv)                                                       \
  }

// GEMM1: h = gelu(x @ W1[e] + b1[e]); A xbf [cb][1024][512], B w1t [E][2048][512]
__global__ __launch_bounds__(512, 2) void k_gemm1(
    const __hip_bfloat16* __restrict__ xbf, const __hip_bfloat16* __restrict__ w1t,
    const float* __restrict__ b1, const int* __restrict__ idx, int b0, int nz,
    __hip_bfloat16* __restrict__ h) {
  constexpr int K = Cc;       // 512
  constexpr int N = HIDc;     // 2048
  constexpr int NT = K / 64;  // 8
  constexpr int NBX = N / 256, NBY = Tc / 256;  // 8, 4
  __shared__ short lds[2][2][256 * 64];  // 128 KB

  int nwg = NBX * NBY * nz;
  int cpx = nwg >> 3;
  int lg = (blockIdx.x & 7) * cpx + (blockIdx.x >> 3);
  int bx = lg % NBX, by = (lg / NBX) % NBY, bz = lg / (NBX * NBY);

  int e = idx[b0 + bz];
  int m0 = by * 256, n0 = bx * 256;
  const short* Ab = (const short*)xbf + ((size_t)bz * Tc + m0) * K;
  const short* Bb = (const short*)w1t + ((size_t)e * N + n0) * K;

  GEMM_PRELUDE(K)
  f4_t acc[8][4] = {};
  KLOOP8(NT)

  // epilogue: bias+gelu -> two-pass per-wave LDS transpose (stride 72)
  __syncthreads();
  short* chunk = &lds[0][0][0] + w * (64 * 72);  // 9216 B per wave
  const float* bias = b1 + (size_t)e * N;
  short* hb = (short*)(h + (size_t)bz * Tc * N);
  int cc2 = (l & 7) * 8;
#pragma unroll
  for (int p = 0; p < 2; ++p) {
#pragma unroll
    for (int fn = 0; fn < 4; ++fn) {
      float bv = bias[n0 + wc * 64 + fn * 16 + (l & 15)];
#pragma unroll
      for (int fm = 0; fm < 4; ++fm) {
        int rl = fm * 16 + ((l >> 4) << 2);
#pragma unroll
        for (int j = 0; j < 4; ++j) {
          float v = gelu_f(acc[p * 4 + fm][fn][j] + bv);
          chunk[(rl + j) * 72 + fn * 16 + (l & 15)] =
              (short)__bfloat16_as_ushort(__float2bfloat16(v));
        }
      }
    }
#pragma unroll
    for (int q = 0; q < 8; ++q) {
      int rr = q * 8 + (l >> 3);
      s8_t v = *(const s8_t*)(chunk + rr * 72 + cc2);
      *(s8_t*)(hb + (size_t)(m0 + wr * 128 + p * 64 + rr) * N + n0 + wc * 64 + cc2) = v;
    }
    // WAR fence: pass-1 LDS writes must not pass pass-0 reads
    asm volatile("s_waitcnt lgkmcnt(0)" ::: "memory");
  }
}

// GEMM2: y = h @ W2[e] + b2[e]; A h [cb][1024][2048], B w2t [E][512][2048]
__global__ __launch_bounds__(512, 2) void k_gemm2(
    const __hip_bfloat16* __restrict__ h, const __hip_bfloat16* __restrict__ w2t,
    const float* __restrict__ b2, const int* __restrict__ idx, int b0, int nz,
    float* __restrict__ out) {
  constexpr int K = HIDc;     // 2048
  constexpr int N = Cc;       // 512
  constexpr int NT = K / 64;  // 32
  constexpr int NBX = N / 256, NBY = Tc / 256;  // 2, 4
  __shared__ short lds[2][2][256 * 64];  // 128 KB

  int nwg = NBX * NBY * nz;  // 8*nz
  int cpx = nwg >> 3;
  int lg = (blockIdx.x & 7) * cpx + (blockIdx.x >> 3);
  int bx = lg % NBX, by = (lg / NBX) % NBY, bz = lg / (NBX * NBY);

  int e = idx[b0 + bz];
  int m0 = by * 256, n0 = bx * 256;
  const short* Ab = (const short*)h + ((size_t)bz * Tc + m0) * K;
  const short* Bb = (const short*)w2t + ((size_t)e * N + n0) * K;

  GEMM_PRELUDE(K)
  f4_t acc[8][4] = {};
  KLOOP8(NT)

  float* ob = out + (size_t)(b0 + bz) * Tc * N;
  const float* bias = b2 + (size_t)e * N;
#pragma unroll
  for (int fn = 0; fn < 4; ++fn) {
    int col = n0 + wc * 64 + fn * 16 + (l & 15);
    float bv = bias[col];
#pragma unroll
    for (int fm = 0; fm < 8; ++fm) {
      int rbase = m0 + wr * 128 + fm * 16 + ((l >> 4) << 2);
#pragma unroll
      for (int j = 0; j < 4; ++j) {
        ob[(size_t)(rbase + j) * N + col] = acc[fm][fn][j] + bv;
      }
    }
  }
}

extern "C" void kernel_launch(void* const* d_in, const int* in_sizes, int n_in,
                              void* d_out, int out_size, void* d_ws, size_t ws_size,
                              hipStream_t stream) {
  const float* x  = (const float*)d_in[0];
  const float* wg = (const float*)d_in[1];
  const float* W1 = (const float*)d_in[2];
  const float* b1 = (const float*)d_in[3];
  const float* W2 = (const float*)d_in[4];
  const float* b2 = (const float*)d_in[5];
  float* out = (float*)d_out;

  char* ws = (char*)d_ws;
  size_t off = 0;
  float* part = (float*)(ws + off); off += (size_t)Bc * 8 * Cc * 4;
  float* logits = (float*)(ws + off); off += (size_t)Bc * Ec * 4;
  int* idx = (int*)(ws + off); off += (size_t)Bc * 4;
  off = (off + 255) & ~(size_t)255;
  __hip_bfloat16* w1t = (__hip_bfloat16*)(ws + off); off += (size_t)Ec * HIDc * Cc * 2;
  __hip_bfloat16* w2t = (__hip_bfloat16*)(ws + off); off += (size_t)Ec * HIDc * Cc * 2;
  size_t dynoff = (off + 255) & ~(size_t)255;

  const size_t x_all = (size_t)Bc * Tc * Cc * 2;   // 64 MB
  const size_t x_per_b = (size_t)Tc * Cc * 2;      // 1 MB
  const size_t h_per_b = (size_t)Tc * HIDc * 2;    // 4 MB

  k_transpose_cvt<<<dim3(HIDc / 32, Cc / 32, Ec), 256, 0, stream>>>(W1, w1t, Cc, HIDc);
  k_transpose_cvt<<<dim3(Cc / 32, HIDc / 32, Ec), 256, 0, stream>>>(W2, w2t, HIDc, Cc);

  if (ws_size >= dynoff + x_all + h_per_b) {
    __hip_bfloat16* xbf = (__hip_bfloat16*)(ws + dynoff);
    __hip_bfloat16* hbf = (__hip_bfloat16*)(ws + dynoff + x_all);
    int cb = (int)((ws_size - dynoff - x_all) / h_per_b);
    if (cb > Bc) cb = Bc;

    k_prep<<<dim3(Bc, 8), 256, 0, stream>>>(x, (ushort*)xbf, part);
    k_xg_logits<<<dim3(Bc), 256, 0, stream>>>(part, wg, logits);
    k_gate<<<dim3(1), 256, 0, stream>>>(logits, idx, out + ((size_t)out_size - 1));

    for (int b0 = 0; b0 < Bc; b0 += cb) {
      int c = (Bc - b0) < cb ? (Bc - b0) : cb;
      const __hip_bfloat16* xc = xbf + (size_t)b0 * Tc * Cc;
      k_gemm1<<<dim3((HIDc / 256) * (Tc / 256) * c), 512, 0, stream>>>(
          xc, w1t, b1, idx, b0, c, hbf);
      k_gemm2<<<dim3((Cc / 256) * (Tc / 256) * c), 512, 0, stream>>>(
          hbf, w2t, b2, idx, b0, c, out);
    }
  } else {
    size_t avail = ws_size > dynoff ? ws_size - dynoff : 0;
    int cb = (int)(avail / (x_per_b + h_per_b));
    if (cb > Bc) cb = Bc;
    if (cb < 1) cb = 1;
    __hip_bfloat16* xbf = (__hip_bfloat16*)(ws + dynoff);
    __hip_bfloat16* hbf = (__hip_bfloat16*)(ws + dynoff + (size_t)cb * x_per_b);

    k_partial<<<dim3(Bc, 8), 256, 0, stream>>>(x, part);
    k_xg_logits<<<dim3(Bc), 256, 0, stream>>>(part, wg, logits);
    k_gate<<<dim3(1), 256, 0, stream>>>(logits, idx, out + ((size_t)out_size - 1));

    for (int b0 = 0; b0 < Bc; b0 += cb) {
      int c = (Bc - b0) < cb ? (Bc - b0) : cb;
      int n4 = c * (Tc * Cc / 4);
      k_cvt_x<<<dim3(1024), 256, 0, stream>>>(x + (size_t)b0 * Tc * Cc, (ushort*)xbf, n4);
      k_gemm1<<<dim3((HIDc / 256) * (Tc / 256) * c), 512, 0, stream>>>(
          xbf, w1t, b1, idx, b0, c, hbf);
      k_gemm2<<<dim3((Cc / 256) * (Tc / 256) * c), 512, 0, stream>>>(
          hbf, w2t, b2, idx, b0, c, out);
    }
  }
}